// Round 5
// baseline (8635.743 us; speedup 1.0000x reference)
//
#include <hip/hip_runtime.h>
#include <math.h>
#include <stdint.h>
#include <stddef.h>

// Problem dims (hard-coded per reference)
#define B_ 512
#define H_ 512
#define E_ 512
#define V_ 2048
#define IN_ 1024
#define LSTEPS 32
#define LP1 33
#define NBLK 256

// JAX threefry mode: 1 = partitionable (JAX >= 0.4.36 default), 0 = original
#define TF_PARTITIONABLE 1

__device__ __forceinline__ void tf2x32(uint32_t k0, uint32_t k1,
                                       uint32_t x0, uint32_t x1,
                                       uint32_t& o0, uint32_t& o1) {
  uint32_t ks2 = k0 ^ k1 ^ 0x1BD11BDAu;
  x0 += k0; x1 += k1;
#define TFR(R) { x0 += x1; x1 = (x1 << (R)) | (x1 >> (32 - (R))); x1 ^= x0; }
  TFR(13) TFR(15) TFR(26) TFR(6)
  x0 += k1; x1 += ks2 + 1u;
  TFR(17) TFR(29) TFR(16) TFR(24)
  x0 += ks2; x1 += k0 + 2u;
  TFR(13) TFR(15) TFR(26) TFR(6)
  x0 += k0; x1 += k1 + 3u;
  TFR(17) TFR(29) TFR(16) TFR(24)
  x0 += k1; x1 += ks2 + 4u;
  TFR(13) TFR(15) TFR(26) TFR(6)
  x0 += ks2; x1 += k0 + 5u;
#undef TFR
  o0 = x0; o1 = x1;
}

// ---- async global->LDS staging helper (16B per lane, wave-uniform LDS base)
typedef __attribute__((address_space(1))) const void GASV;
typedef __attribute__((address_space(3))) void LASV;
__device__ __forceinline__ void gld16(const void* g, void* l) {
  __builtin_amdgcn_global_load_lds((GASV*)g, (LASV*)l, 16, 0, 0);
}

__device__ __forceinline__ float sigm(float x) { return 1.0f / (1.0f + expf(-x)); }

__global__ void bar_init_kernel(unsigned int* bar) {
  if (threadIdx.x < 2) bar[threadIdx.x] = 0u;
}

// Software grid barrier: 256 blocks are always co-resident (256 blocks, 64KB LDS,
// ~130 VGPR -> worst-case capacity >= 512 blocks), so spin is deadlock-free.
__device__ __forceinline__ void grid_barrier(unsigned int* bar) {
  __threadfence();
  __syncthreads();
  if (threadIdx.x == 0) {
    unsigned int g0 = __hip_atomic_load(&bar[1], __ATOMIC_ACQUIRE, __HIP_MEMORY_SCOPE_AGENT);
    unsigned int a = __hip_atomic_fetch_add(&bar[0], 1u, __ATOMIC_ACQ_REL, __HIP_MEMORY_SCOPE_AGENT);
    if (a == NBLK - 1u) {
      __hip_atomic_store(&bar[0], 0u, __ATOMIC_RELAXED, __HIP_MEMORY_SCOPE_AGENT);
      __hip_atomic_fetch_add(&bar[1], 1u, __ATOMIC_RELEASE, __HIP_MEMORY_SCOPE_AGENT);
    } else {
      while (__hip_atomic_load(&bar[1], __ATOMIC_ACQUIRE, __HIP_MEMORY_SCOPE_AGENT) == g0) {
        __builtin_amdgcn_s_sleep(1);
      }
    }
  }
  __syncthreads();
  __threadfence();
}

// One wave computes a 64x64 fp32 tile over its K-range (nch chunks of 16).
// Av: 64 rows (row stride sA), local k from 0. Bv: local k rows (stride sB),
// per-lane global col offset bcolg. wl: this wave's private 4096-float LDS region
// (A0|B0|A1|B1 of 1024 floats each). 8x8 micro-tile, all ds_read_b128.
// A LDS layout [row][16k] with granule swizzle p = kg ^ (row&3) so fragment
// reads are <=2-way bank aliases while staying global_load_lds compatible.
__device__ __forceinline__ void wave_gemm64(
    const float* __restrict__ Av, int sA,
    const float* __restrict__ Bv, int sB, int bcolg,
    int nch, float* __restrict__ wl, int l, float acc[8][8]) {
  const int arow = l >> 2;
  const int aswz = ((l & 3) ^ ((l >> 2) & 3)) << 2;
  const int bkr = l >> 4;
  const int ly = l & 7, lx = l >> 3;
  float* A0 = wl;        float* B0 = wl + 1024;
  float* A1 = wl + 2048; float* B1 = wl + 3072;
#define WG_STAGE(KC, Ab, Bb) {                                                  \
    _Pragma("unroll")                                                           \
    for (int j = 0; j < 4; j++) {                                               \
      gld16(Av + (size_t)(j * 16 + arow) * sA + (KC) + aswz, (Ab) + j * 256);   \
      gld16(Bv + (size_t)((KC) + j * 4 + bkr) * sB + bcolg, (Bb) + j * 256);    \
    }                                                                           \
  }
  WG_STAGE(0, A0, B0)
  for (int ch = 0; ch < nch; ch++) {
    __syncthreads();                       // drains vmcnt: buf[ch&1] ready
    if (ch + 1 < nch) {
      if ((ch + 1) & 1) WG_STAGE((ch + 1) * 16, A1, B1)
      else              WG_STAGE((ch + 1) * 16, A0, B0)
    }
    const float* Ab = (ch & 1) ? A1 : A0;
    const float* Bb = (ch & 1) ? B1 : B0;
#pragma unroll
    for (int kg = 0; kg < 4; kg++) {
      const int pgr = (kg ^ (ly & 3)) << 2;
      float4 a[8];
#pragma unroll
      for (int i = 0; i < 8; i++)
        a[i] = *(const float4*)&Ab[(ly + 8 * i) * 16 + pgr];
#pragma unroll
      for (int kk = 0; kk < 4; kk++) {
        float4 b0 = *(const float4*)&Bb[(kg * 4 + kk) * 64 + lx * 8];
        float4 b1 = *(const float4*)&Bb[(kg * 4 + kk) * 64 + lx * 8 + 4];
#pragma unroll
        for (int i = 0; i < 8; i++) {
          float av = ((const float*)&a[i])[kk];
          acc[i][0] += av * b0.x; acc[i][1] += av * b0.y;
          acc[i][2] += av * b0.z; acc[i][3] += av * b0.w;
          acc[i][4] += av * b1.x; acc[i][5] += av * b1.y;
          acc[i][6] += av * b1.z; acc[i][7] += av * b1.w;
        }
      }
    }
  }
#undef WG_STAGE
}

// Store wave's 64x64 partial into its LDS region as [row][col].
__device__ __forceinline__ void wave_store_partial(float* dst, int l, const float acc[8][8]) {
  const int ly = l & 7, lx = l >> 3;
#pragma unroll
  for (int i = 0; i < 8; i++) {
    int r = ly + 8 * i;
    *(float4*)&dst[r * 64 + lx * 8] = make_float4(acc[i][0], acc[i][1], acc[i][2], acc[i][3]);
    *(float4*)&dst[r * 64 + lx * 8 + 4] = make_float4(acc[i][4], acc[i][5], acc[i][6], acc[i][7]);
  }
}

// Sum the 4 per-wave partials in LDS + bias, store 64x64 tile to dst.
__device__ __forceinline__ void reduce_bias_store(
    const float* __restrict__ bias, float* __restrict__ dst, int dstride,
    int rowbase, int colbase, int tid, const float* __restrict__ lds) {
  int cq = tid & 15, rg = tid >> 4;
  int gc = colbase + cq * 4;
  float4 bz = *(const float4*)&bias[gc];
#pragma unroll
  for (int q = 0; q < 4; q++) {
    int r = rg * 4 + q;
    float4 s = bz;
#pragma unroll
    for (int wv = 0; wv < 4; wv++) {
      float4 p = *(const float4*)&lds[wv * 4096 + r * 64 + cq * 4];
      s.x += p.x; s.y += p.y; s.z += p.z; s.w += p.w;
    }
    *(float4*)&dst[(size_t)(rowbase + r) * dstride + gc] = s;
  }
}

__global__ __launch_bounds__(256) void mega_kernel(
    const float* __restrict__ x, const float* __restrict__ agw,
    const float* __restrict__ agb, const float* __restrict__ sos,
    const float* __restrict__ emb, const float* __restrict__ w_ih,
    const float* __restrict__ w_hh, const float* __restrict__ b_ih,
    const float* __restrict__ b_hh, const float* __restrict__ out_w,
    const float* __restrict__ out_b,
    unsigned int* __restrict__ bar, uint32_t* __restrict__ sk,
    float* __restrict__ e_ws, float* __restrict__ hA, float* __restrict__ hB,
    float* __restrict__ c_ws, float* __restrict__ z_ws,
    float* __restrict__ o_seq, float* __restrict__ o_probs,
    float* __restrict__ o_logp, float* __restrict__ o_ent) {
  __shared__ float lds[16384];   // 64 KB: 4 waves x (A0|B0|A1|B1) / partial tiles
  int tid = threadIdx.x;
  int b = blockIdx.x;

  // ---- init phase: c=0, e=sos, EOS outputs, threefry keys
  {
    int gid = b * 256 + tid;                       // 0..65535
    ((float4*)c_ws)[gid] = make_float4(0.f, 0.f, 0.f, 0.f);
    ((float4*)e_ws)[gid] = ((const float4*)sos)[gid & 127];
    float4 ones = make_float4(1.f, 1.f, 1.f, 1.f);
#pragma unroll
    for (int i = 0; i < 4; i++) {
      int f = gid + i * 65536;                     // 262144 float4s of probs EOS
      int row = f >> 9, col4 = f & 511;
      ((float4*)(o_probs + ((size_t)row * LP1 + LSTEPS) * V_))[col4] = ones;
    }
    if (gid < B_) {
      o_seq[gid * LP1 + LSTEPS] = 0.f;
      o_logp[gid * LP1 + LSTEPS] = 0.f;
      o_ent[gid * LP1 + LSTEPS] = 0.f;
    }
    if (gid == 0) {
      uint32_t k0 = 0u, k1 = 1u;
      for (int t = 0; t < LSTEPS; t++) {
        uint32_t a0, a1, c0, c1;
#if TF_PARTITIONABLE
        tf2x32(k0, k1, 0u, 0u, a0, a1);
        tf2x32(k0, k1, 0u, 1u, c0, c1);
        sk[2 * t] = c0; sk[2 * t + 1] = c1;
        k0 = a0; k1 = a1;
#else
        tf2x32(k0, k1, 0u, 2u, a0, a1);
        tf2x32(k0, k1, 1u, 3u, c0, c1);
        sk[2 * t] = a1; sk[2 * t + 1] = c1;
        k0 = a0; k1 = c0;
#endif
      }
    }
  }
  grid_barrier(bar);

  // ---- h0 = x @ agent_w + agent_b (blocks 0..63)
  if (b < 64) {
    int bm = b >> 3, bn = b & 7;
    int w = tid >> 6, l = tid & 63;
    float acc[8][8] = {};
    wave_gemm64(x + (size_t)(bm * 64) * IN_ + w * 256, IN_,
                agw + (size_t)(w * 256) * H_, H_,
                bn * 64 + (l & 15) * 4, 16, lds + w * 4096, l, acc);
    wave_store_partial(lds + w * 4096, l, acc);
    __syncthreads();
    reduce_bias_store(agb, hA, H_, bm * 64, bn * 64, tid, lds);
  }
  grid_barrier(bar);

  for (int t = 0; t < LSTEPS; t++) {
    float* hi = (t & 1) ? hB : hA;
    float* ho = (t & 1) ? hA : hB;

    // ---- gates GEMM (K=1024, 4-way K-split by wave) + fused LSTM cell.
    // Tile cols are gate-interleaved: tile col c -> gate c>>4, hcol bn*16+(c&15).
    {
      int bm = b >> 5, bn = b & 31;
      int w = tid >> 6, l = tid & 63;
      float acc[8][8] = {};
      const float* Av; const float* Bv;
      if (w < 2) { Av = e_ws + (size_t)(bm * 64) * E_ + w * 256;
                   Bv = w_ih + (size_t)(w * 256) * 2048; }
      else       { Av = hi + (size_t)(bm * 64) * H_ + (w - 2) * 256;
                   Bv = w_hh + (size_t)((w - 2) * 256) * 2048; }
      int bcolg = ((l & 15) >> 2) * 512 + bn * 16 + (l & 3) * 4;
      wave_gemm64(Av, 512, Bv, 2048, bcolg, 16, lds + w * 4096, l, acc);
      wave_store_partial(lds + w * 4096, l, acc);
      __syncthreads();
      int hl = tid & 15, rg = tid >> 4;
      int gcol = bn * 16 + hl;
      float bI = b_ih[gcol] + b_hh[gcol];
      float bF = b_ih[H_ + gcol] + b_hh[H_ + gcol];
      float bG = b_ih[2 * H_ + gcol] + b_hh[2 * H_ + gcol];
      float bO = b_ih[3 * H_ + gcol] + b_hh[3 * H_ + gcol];
#pragma unroll
      for (int q = 0; q < 4; q++) {
        int r = rg * 4 + q;
        float gi = bI, gf = bF, gg2 = bG, go = bO;
#pragma unroll
        for (int wv = 0; wv < 4; wv++) {
          const float* rp = lds + wv * 4096 + r * 64;
          gi += rp[hl]; gf += rp[16 + hl]; gg2 += rp[32 + hl]; go += rp[48 + hl];
        }
        size_t ci = (size_t)(bm * 64 + r) * H_ + gcol;
        float cv = sigm(gf) * c_ws[ci] + sigm(gi) * tanhf(gg2);
        c_ws[ci] = cv;
        ho[ci] = sigm(go) * tanhf(cv);
      }
    }
    grid_barrier(bar);

    // ---- logits = h @ out_w + out_b (K=512, 4-way K-split by wave)
    {
      int bm = b >> 5, bn = b & 31;
      int w = tid >> 6, l = tid & 63;
      float acc[8][8] = {};
      wave_gemm64(ho + (size_t)(bm * 64) * H_ + w * 128, H_,
                  out_w + (size_t)(w * 128) * V_, V_,
                  bn * 64 + (l & 15) * 4, 8, lds + w * 4096, l, acc);
      wave_store_partial(lds + w * 4096, l, acc);
      __syncthreads();
      reduce_bias_store(out_b, z_ws, V_, bm * 64, bn * 64, tid, lds);
    }
    grid_barrier(bar);

    // ---- sampler: rows 2b, 2b+1; softmax/entropy/probs/gumbel-argmax/embed
    for (int rr = 0; rr < 2; rr++) {
      int row = b * 2 + rr;
      float* zs = lds;                 // 2048 floats
      float* rmax = lds + 2048; float* rsum = lds + 2056;
      float* rps = lds + 2064;  float* rav = lds + 2072;
      int* rai = (int*)(lds + 2080);
      int wid = tid >> 6;
      const float* zrow = z_ws + (size_t)row * V_;
      float4 za = *(const float4*)(zrow + tid * 8);
      float4 zb = *(const float4*)(zrow + tid * 8 + 4);
      float zv[8] = {za.x, za.y, za.z, za.w, zb.x, zb.y, zb.z, zb.w};
      *(float4*)&zs[tid * 8] = za;
      *(float4*)&zs[tid * 8 + 4] = zb;

      float m = zv[0];
#pragma unroll
      for (int i = 1; i < 8; i++) m = fmaxf(m, zv[i]);
      for (int off = 32; off; off >>= 1) m = fmaxf(m, __shfl_xor(m, off));
      if ((tid & 63) == 0) rmax[wid] = m;
      __syncthreads();
      m = fmaxf(fmaxf(rmax[0], rmax[1]), fmaxf(rmax[2], rmax[3]));

      float sh[8];
      float ssum = 0.f;
#pragma unroll
      for (int i = 0; i < 8; i++) { sh[i] = zv[i] - m; ssum += expf(sh[i]); }
      for (int off = 32; off; off >>= 1) ssum += __shfl_xor(ssum, off);
      if ((tid & 63) == 0) rsum[wid] = ssum;
      __syncthreads();
      float S = (rsum[0] + rsum[1]) + (rsum[2] + rsum[3]);
      float ls = logf(S);

      uint32_t sk0 = sk[2 * t], sk1 = sk[2 * t + 1];
      float psum = 0.f;
      float best = -INFINITY;
      int bi = 0;
      float pv[8];
#pragma unroll
      for (int i = 0; i < 8; i++) {
        float s = sh[i] - ls;
        float p = expf(s);
        pv[i] = p;
        psum += p * s;
        int v = tid * 8 + i;
        uint32_t o0, o1, bits;
#if TF_PARTITIONABLE
        uint32_t j = (uint32_t)(row * V_ + v);
        tf2x32(sk0, sk1, 0u, j, o0, o1);
        bits = o0 ^ o1;
#else
        uint32_t j = (uint32_t)(row * V_ + v);
        const uint32_t n2 = (uint32_t)(B_ * V_ / 2);
        if (j < n2) { tf2x32(sk0, sk1, j, j + n2, o0, o1); bits = o0; }
        else        { tf2x32(sk0, sk1, j - n2, j, o0, o1); bits = o1; }
#endif
        float f = __uint_as_float((bits >> 9) | 0x3f800000u) - 1.0f;
        float u = fmaxf(f, 1.17549435e-38f);
        float g = -logf(-logf(u));
        float aa = s + g;
        if (aa > best) { best = aa; bi = v; }
      }
      float* prw = o_probs + ((size_t)row * LP1 + t) * V_ + tid * 8;
      *(float4*)prw = make_float4(pv[0], pv[1], pv[2], pv[3]);
      *(float4*)(prw + 4) = make_float4(pv[4], pv[5], pv[6], pv[7]);

      for (int off = 32; off; off >>= 1) psum += __shfl_xor(psum, off);
      for (int off = 32; off; off >>= 1) {
        float ov = __shfl_xor(best, off);
        int oi = __shfl_xor(bi, off);
        if (ov > best || (ov == best && oi < bi)) { best = ov; bi = oi; }
      }
      if ((tid & 63) == 0) { rps[wid] = psum; rav[wid] = best; rai[wid] = bi; }
      __syncthreads();
      float ent = -((rps[0] + rps[1]) + (rps[2] + rps[3]));
      float bv2 = rav[0]; int sym = rai[0];
#pragma unroll
      for (int w2 = 1; w2 < 4; w2++) {
        if (rav[w2] > bv2 || (rav[w2] == bv2 && rai[w2] < sym)) { bv2 = rav[w2]; sym = rai[w2]; }
      }
      // next embedding (E_=512 floats = 128 float4)
      if (tid < 128) {
        ((float4*)(e_ws + (size_t)row * E_))[tid] =
            ((const float4*)(emb + (size_t)sym * E_))[tid];
      }
      if (tid == 0) {
        float s_sym = (zs[sym] - m) - ls;
        o_seq[row * LP1 + t] = (float)sym;
        o_logp[row * LP1 + t] = s_sym;
        o_ent[row * LP1 + t] = ent;
      }
      __syncthreads();   // protect zs before next row reuses it
    }
    grid_barrier(bar);
  }
}

extern "C" void kernel_launch(void* const* d_in, const int* in_sizes, int n_in,
                              void* d_out, int out_size, void* d_ws, size_t ws_size,
                              hipStream_t stream) {
  (void)in_sizes; (void)n_in; (void)out_size; (void)ws_size;
  const float* x     = (const float*)d_in[0];
  const float* agw   = (const float*)d_in[1];
  const float* agb   = (const float*)d_in[2];
  const float* sos   = (const float*)d_in[3];
  const float* emb   = (const float*)d_in[4];
  const float* w_ih  = (const float*)d_in[5];
  const float* w_hh  = (const float*)d_in[6];
  const float* b_ih  = (const float*)d_in[7];
  const float* b_hh  = (const float*)d_in[8];
  const float* out_w = (const float*)d_in[9];
  const float* out_b = (const float*)d_in[10];

  char* w = (char*)d_ws;
  unsigned int* bar = (unsigned int*)w;                       // 64 B
  uint32_t* sk = (uint32_t*)(w + 256);                        // 256 B
  float* e  = (float*)(w + 4096);                             // 1 MB
  float* hA = (float*)(w + 4096 + 1 * 1048576);               // 1 MB
  float* hB = (float*)(w + 4096 + 2 * 1048576);               // 1 MB
  float* c  = (float*)(w + 4096 + 3 * 1048576);               // 1 MB
  float* z  = (float*)(w + 4096 + 4 * 1048576);               // 4 MB

  float* out = (float*)d_out;
  float* o_seq   = out;                                       // [512,33]
  float* o_probs = out + (size_t)B_ * LP1;                    // [512,33,2048]
  float* o_logp  = o_probs + (size_t)B_ * LP1 * V_;           // [512,33]
  float* o_ent   = o_logp + (size_t)B_ * LP1;                 // [512,33]

  bar_init_kernel<<<1, 64, 0, stream>>>(bar);
  mega_kernel<<<NBLK, 256, 0, stream>>>(
      x, agw, agb, sos, emb, w_ih, w_hh, b_ih, b_hh, out_w, out_b,
      bar, sk, e, hA, hB, c, z, o_seq, o_probs, o_logp, o_ent);
}